// Round 1
// baseline (936.230 us; speedup 1.0000x reference)
//
#include <hip/hip_runtime.h>
#include <math.h>

// ---------------- helpers ----------------

__device__ __forceinline__ unsigned fkey(float f) {
  unsigned u = __float_as_uint(f);
  return (u & 0x80000000u) ? ~u : (u | 0x80000000u);
}
__device__ __forceinline__ float funkey(unsigned k) {
  unsigned u = (k & 0x80000000u) ? (k ^ 0x80000000u) : ~k;
  return __uint_as_float(u);
}

// ---------------- init ----------------

__global__ void init_kernel(int* __restrict__ deg, unsigned* __restrict__ pooledU,
                            unsigned* __restrict__ cmaxU, float* __restrict__ denom,
                            int* __restrict__ cnt, int n, int gh, int g) {
  int i = blockIdx.x * blockDim.x + threadIdx.x;
  if (i < n) deg[i] = 0;
  if (i < gh) pooledU[i] = 0x80000000u;  // key(0.0f)
  if (i < g) { cmaxU[i] = 0u; denom[i] = 0.f; cnt[i] = 0; }
}

// ---------------- CSR build ----------------

__global__ void hist_kernel(const int* __restrict__ dst, int* __restrict__ deg, int E) {
  int e = blockIdx.x * blockDim.x + threadIdx.x;
  if (e < E) atomicAdd(&deg[dst[e]], 1);
}

__global__ void __launch_bounds__(1024) scan_kernel(const int* __restrict__ deg,
                                                    int* __restrict__ rowptr,
                                                    int* __restrict__ cursor, int n) {
  __shared__ int wsum[16];
  __shared__ int carryS;
  const int tid = threadIdx.x, lane = tid & 63, wid = tid >> 6;
  if (tid == 0) carryS = 0;
  __syncthreads();
  const int CH = 1024 * 4;
  for (int base = 0; base < n; base += CH) {
    int i0 = base + tid * 4;
    int v[4];
#pragma unroll
    for (int k = 0; k < 4; ++k) { int i = i0 + k; v[k] = (i < n) ? deg[i] : 0; }
    int s = v[0] + v[1] + v[2] + v[3];
    int sc = s;
#pragma unroll
    for (int off = 1; off < 64; off <<= 1) {
      int t = __shfl_up(sc, off);
      if (lane >= off) sc += t;
    }
    if (lane == 63) wsum[wid] = sc;
    __syncthreads();
    if (wid == 0) {
      int ws = (lane < 16) ? wsum[lane] : 0;
#pragma unroll
      for (int off = 1; off < 16; off <<= 1) {
        int t = __shfl_up(ws, off);
        if (lane >= off) ws += t;
      }
      if (lane < 16) wsum[lane] = ws;
    }
    __syncthreads();
    int waveoff = (wid > 0) ? wsum[wid - 1] : 0;
    int excl = carryS + waveoff + (sc - s);
#pragma unroll
    for (int k = 0; k < 4; ++k) {
      int i = i0 + k;
      if (i < n) { rowptr[i] = excl; cursor[i] = excl; }
      excl += v[k];
    }
    __syncthreads();
    if (tid == 0) carryS += wsum[15];
    __syncthreads();
  }
  if (tid == 0) rowptr[n] = carryS;
}

__global__ void scatter_kernel(const int* __restrict__ src, const int* __restrict__ dst,
                               int* __restrict__ cursor, int* __restrict__ csr, int E) {
  int e = blockIdx.x * blockDim.x + threadIdx.x;
  if (e < E) {
    int d = dst[e];
    int pos = atomicAdd(&cursor[d], 1);
    csr[pos] = src[e];
  }
}

// ---------------- fused SAGE layer (agg-max + dual matvec + relu) ----------------
// One wave handles 8 nodes: aggregate into per-wave LDS, then lane = out-feature.

template <int F>
__global__ void __launch_bounds__(256, 2) sage_layer(
    const float* __restrict__ xin, const int* __restrict__ rowptr,
    const int* __restrict__ csr, const float* __restrict__ Wl,
    const float* __restrict__ bl, const float* __restrict__ Wr,
    float* __restrict__ xout, int nn) {
  constexpr int NPW = 8;
  const int lane = threadIdx.x & 63;
  const int wid = threadIdx.x >> 6;
  const int base = (blockIdx.x * 4 + wid) * NPW;
  __shared__ float smem[4][2][NPW][F];
  float(*aggS)[F] = smem[wid][0];
  float(*selfS)[F] = smem[wid][1];

  for (int j = 0; j < NPW; ++j) {
    int n = base + j;
    if constexpr (F == 128) {
      float2 m = make_float2(0.f, 0.f), sv = make_float2(0.f, 0.f);
      if (n < nn) {
        sv = ((const float2*)(xin + (size_t)n * F))[lane];
        int k0 = rowptr[n], k1 = rowptr[n + 1];
        if (k1 > k0) {
          m = make_float2(-INFINITY, -INFINITY);
          int k = k0;
          for (; k + 4 <= k1; k += 4) {
            int s0 = csr[k], s1 = csr[k + 1], s2 = csr[k + 2], s3 = csr[k + 3];
            float2 a = ((const float2*)(xin + (size_t)s0 * F))[lane];
            float2 b = ((const float2*)(xin + (size_t)s1 * F))[lane];
            float2 c = ((const float2*)(xin + (size_t)s2 * F))[lane];
            float2 d = ((const float2*)(xin + (size_t)s3 * F))[lane];
            m.x = fmaxf(m.x, fmaxf(fmaxf(a.x, b.x), fmaxf(c.x, d.x)));
            m.y = fmaxf(m.y, fmaxf(fmaxf(a.y, b.y), fmaxf(c.y, d.y)));
          }
          for (; k < k1; ++k) {
            float2 a = ((const float2*)(xin + (size_t)csr[k] * F))[lane];
            m.x = fmaxf(m.x, a.x);
            m.y = fmaxf(m.y, a.y);
          }
        }
      }
      ((float2*)aggS[j])[lane] = m;
      ((float2*)selfS[j])[lane] = sv;
    } else {
      float m = 0.f, sv = 0.f;
      if (n < nn) {
        sv = xin[(size_t)n * F + lane];
        int k0 = rowptr[n], k1 = rowptr[n + 1];
        if (k1 > k0) {
          m = -INFINITY;
          int k = k0;
          for (; k + 4 <= k1; k += 4) {
            int s0 = csr[k], s1 = csr[k + 1], s2 = csr[k + 2], s3 = csr[k + 3];
            float a = xin[(size_t)s0 * F + lane];
            float b = xin[(size_t)s1 * F + lane];
            float c = xin[(size_t)s2 * F + lane];
            float d = xin[(size_t)s3 * F + lane];
            m = fmaxf(m, fmaxf(fmaxf(a, b), fmaxf(c, d)));
          }
          for (; k < k1; ++k) m = fmaxf(m, xin[(size_t)csr[k] * F + lane]);
        }
      }
      aggS[j][lane] = m;
      selfS[j][lane] = sv;
    }
  }
  // no __syncthreads needed: each wave reads only its own LDS region

  float acc[NPW];
  const float bias = bl[lane];
#pragma unroll
  for (int j = 0; j < NPW; ++j) acc[j] = bias;
  for (int f = 0; f < F; f += 4) {
    float wl0 = Wl[(f + 0) * 64 + lane], wl1 = Wl[(f + 1) * 64 + lane];
    float wl2 = Wl[(f + 2) * 64 + lane], wl3 = Wl[(f + 3) * 64 + lane];
    float wr0 = Wr[(f + 0) * 64 + lane], wr1 = Wr[(f + 1) * 64 + lane];
    float wr2 = Wr[(f + 2) * 64 + lane], wr3 = Wr[(f + 3) * 64 + lane];
#pragma unroll
    for (int j = 0; j < NPW; ++j) {
      float4 a = *(const float4*)&aggS[j][f];
      float4 s = *(const float4*)&selfS[j][f];
      acc[j] = fmaf(a.x, wl0, acc[j]);
      acc[j] = fmaf(a.y, wl1, acc[j]);
      acc[j] = fmaf(a.z, wl2, acc[j]);
      acc[j] = fmaf(a.w, wl3, acc[j]);
      acc[j] = fmaf(s.x, wr0, acc[j]);
      acc[j] = fmaf(s.y, wr1, acc[j]);
      acc[j] = fmaf(s.z, wr2, acc[j]);
      acc[j] = fmaf(s.w, wr3, acc[j]);
    }
  }
#pragma unroll
  for (int j = 0; j < NPW; ++j) {
    int n = base + j;
    if (n < nn) xout[(size_t)n * 64 + lane] = fmaxf(acc[j], 0.f);
  }
}

// ---------------- pooling tail ----------------

__global__ void cscore_kernel(const float* __restrict__ clo, const float* __restrict__ Wc,
                              const float* __restrict__ bc, const int* __restrict__ bat,
                              float* __restrict__ cbuf, unsigned* __restrict__ cmaxU,
                              int* __restrict__ cnt, int n) {
  int i = blockIdx.x * blockDim.x + threadIdx.x;
  int lane = threadIdx.x & 63;
  float cv = -INFINITY;
  int g = -1;
  if (i < n) {
    const float4* row = (const float4*)(clo + (size_t)i * 16);
    float4 r0 = row[0], r1 = row[1], r2 = row[2], r3 = row[3];
    cv = bc[0];
    cv += r0.x * Wc[0] + r0.y * Wc[1] + r0.z * Wc[2] + r0.w * Wc[3];
    cv += r1.x * Wc[4] + r1.y * Wc[5] + r1.z * Wc[6] + r1.w * Wc[7];
    cv += r2.x * Wc[8] + r2.y * Wc[9] + r2.z * Wc[10] + r2.w * Wc[11];
    cv += r3.x * Wc[12] + r3.y * Wc[13] + r3.z * Wc[14] + r3.w * Wc[15];
    cbuf[i] = cv;
    g = bat[i];
  }
  int g0 = __shfl(g, 0), g63 = __shfl(g, 63);
  if (g0 >= 0 && g0 == g63) {  // whole wave in one graph (batch sorted)
    float m = cv;
#pragma unroll
    for (int off = 32; off; off >>= 1) m = fmaxf(m, __shfl_down(m, off));
    if (lane == 0) {
      atomicMax(&cmaxU[g0], fkey(m));
      atomicAdd(&cnt[g0], 64);
    }
  } else if (g >= 0) {
    atomicMax(&cmaxU[g], fkey(cv));
    atomicAdd(&cnt[g], 1);
  }
}

__global__ void esum_kernel(const float* __restrict__ cbuf, const int* __restrict__ bat,
                            const unsigned* __restrict__ cmaxU, float* __restrict__ ebuf,
                            float* __restrict__ denom, int n) {
  int i = blockIdx.x * blockDim.x + threadIdx.x;
  int lane = threadIdx.x & 63;
  float ev = 0.f;
  int g = -1;
  if (i < n) {
    g = bat[i];
    float cm = funkey(cmaxU[g]);
    ev = expf(cbuf[i] - cm);
    ebuf[i] = ev;
  }
  int g0 = __shfl(g, 0), g63 = __shfl(g, 63);
  if (g0 >= 0 && g0 == g63) {
    float s = ev;
#pragma unroll
    for (int off = 32; off; off >>= 1) s += __shfl_down(s, off);
    if (lane == 0) atomicAdd(&denom[g0], s);
  } else if (g >= 0) {
    atomicAdd(&denom[g], ev);
  }
}

__global__ void pool_kernel(const float* __restrict__ ebuf, const float* __restrict__ denom,
                            const int* __restrict__ cnt, const int* __restrict__ bat,
                            const float* __restrict__ h3, unsigned* __restrict__ pooledU,
                            int n) {
  const int CH = 64;
  int wave = (blockIdx.x * blockDim.x + threadIdx.x) >> 6;
  int lane = threadIdx.x & 63;
  int nb = wave * CH;
  if (nb >= n) return;
  int ne = min(nb + CH, n);
  int curg = bat[nb];
  float factor = (float)cnt[curg] / denom[curg];
  float lmax = -INFINITY;
  for (int nd = nb; nd < ne; ++nd) {
    int g = bat[nd];
    if (g != curg) {
      atomicMax(&pooledU[(size_t)curg * 64 + lane], fkey(lmax));
      curg = g;
      factor = (float)cnt[g] / denom[g];
      lmax = -INFINITY;
    }
    float v = ebuf[nd] * factor * h3[(size_t)nd * 64 + lane];
    lmax = fmaxf(lmax, v);
  }
  atomicMax(&pooledU[(size_t)curg * 64 + lane], fkey(lmax));
}

__global__ void final_kernel(const unsigned* __restrict__ pooledU, const float* __restrict__ Wa1,
                             const float* __restrict__ ba1, const float* __restrict__ Wa2,
                             const float* __restrict__ ba2, float* __restrict__ out, int G) {
  int g = blockIdx.x;
  int lane = threadIdx.x;  // block = 64
  float v = funkey(pooledU[(size_t)g * 64 + lane]);
  if (!isfinite(v)) v = 0.f;  // empty-graph / safety, matches jnp.where(isfinite)
  float outv = 0.f;
#pragma unroll
  for (int j = 0; j < 16; ++j) {
    float psum = v * Wa1[lane * 16 + j];
#pragma unroll
    for (int off = 32; off; off >>= 1) psum += __shfl_down(psum, off);
    if (lane == 0) outv += fmaxf(psum + ba1[j], 0.f) * Wa2[j];
  }
  if (lane == 0) out[g] = outv + ba2[0];
}

// ---------------- launch ----------------

static inline size_t alignup(size_t x) { return (x + 255) & ~(size_t)255; }

extern "C" void kernel_launch(void* const* d_in, const int* in_sizes, int n_in,
                              void* d_out, int out_size, void* d_ws, size_t ws_size,
                              hipStream_t stream) {
  const float* x = (const float*)d_in[0];
  const int* ei = (const int*)d_in[1];
  const int* bat = (const int*)d_in[2];
  const float* clo = (const float*)d_in[3];
  const float* W1l = (const float*)d_in[4];
  const float* b1l = (const float*)d_in[5];
  const float* W1r = (const float*)d_in[6];
  const float* W2l = (const float*)d_in[7];
  const float* b2l = (const float*)d_in[8];
  const float* W2r = (const float*)d_in[9];
  const float* W3l = (const float*)d_in[10];
  const float* b3l = (const float*)d_in[11];
  const float* W3r = (const float*)d_in[12];
  const float* Wc = (const float*)d_in[13];
  const float* bc = (const float*)d_in[14];
  const float* Wa1 = (const float*)d_in[15];
  const float* ba1 = (const float*)d_in[16];
  const float* Wa2 = (const float*)d_in[17];
  const float* ba2 = (const float*)d_in[18];
  float* out = (float*)d_out;

  const int N = in_sizes[2];
  const int E = in_sizes[1] / 2;
  const int G = out_size;

  char* p = (char*)d_ws;
  auto carve = [&](size_t bytes) {
    char* r = p;
    p += alignup(bytes);
    return r;
  };
  int* deg = (int*)carve((size_t)N * 4);
  int* rowptr = (int*)carve((size_t)(N + 1) * 4);
  int* cursor = (int*)carve((size_t)N * 4);
  int* csr = (int*)carve((size_t)E * 4);
  float* hA = (float*)carve((size_t)N * 64 * 4);
  float* hB = (float*)carve((size_t)N * 64 * 4);
  float* cbuf = (float*)carve((size_t)N * 4);
  float* ebuf = (float*)carve((size_t)N * 4);
  unsigned* cmaxU = (unsigned*)carve((size_t)G * 4);
  float* denom = (float*)carve((size_t)G * 4);
  int* cnt = (int*)carve((size_t)G * 4);
  unsigned* pooledU = (unsigned*)carve((size_t)G * 64 * 4);

  const int* srcv = ei;
  const int* dstv = ei + E;

  int nb = (N + 255) / 256;
  hipLaunchKernelGGL(init_kernel, dim3(nb), dim3(256), 0, stream, deg, pooledU, cmaxU, denom,
                     cnt, N, G * 64, G);
  hipLaunchKernelGGL(hist_kernel, dim3((E + 255) / 256), dim3(256), 0, stream, dstv, deg, E);
  hipLaunchKernelGGL(scan_kernel, dim3(1), dim3(1024), 0, stream, deg, rowptr, cursor, N);
  hipLaunchKernelGGL(scatter_kernel, dim3((E + 255) / 256), dim3(256), 0, stream, srcv, dstv,
                     cursor, csr, E);

  int nblocks32 = (N + 31) / 32;
  hipLaunchKernelGGL((sage_layer<128>), dim3(nblocks32), dim3(256), 0, stream, x, rowptr, csr,
                     W1l, b1l, W1r, hA, N);
  hipLaunchKernelGGL((sage_layer<64>), dim3(nblocks32), dim3(256), 0, stream, hA, rowptr, csr,
                     W2l, b2l, W2r, hB, N);
  hipLaunchKernelGGL((sage_layer<64>), dim3(nblocks32), dim3(256), 0, stream, hB, rowptr, csr,
                     W3l, b3l, W3r, hA, N);

  hipLaunchKernelGGL(cscore_kernel, dim3(nb), dim3(256), 0, stream, clo, Wc, bc, bat, cbuf,
                     cmaxU, cnt, N);
  hipLaunchKernelGGL(esum_kernel, dim3(nb), dim3(256), 0, stream, cbuf, bat, cmaxU, ebuf, denom,
                     N);
  int pw = (N + 63) / 64;
  int pb = (pw + 3) / 4;
  hipLaunchKernelGGL(pool_kernel, dim3(pb), dim3(256), 0, stream, ebuf, denom, cnt, bat, hA,
                     pooledU, N);
  hipLaunchKernelGGL(final_kernel, dim3(G), dim3(64), 0, stream, pooledU, Wa1, ba1, Wa2, ba2,
                     out, G);
}